// Round 6
// baseline (272.032 us; speedup 1.0000x reference)
//
#include <hip/hip_runtime.h>
#include <hip/hip_bf16.h>

#define NN 50000
#define NE 600000
#define DD 128
#define NR 8
#define NCHUNK ((NN + 255) / 256)   // 196 scan blocks

typedef __attribute__((ext_vector_type(8))) short bf16x8;
typedef __attribute__((ext_vector_type(4))) float f32x4;

__device__ __forceinline__ unsigned short f2bf(float f) {
  __hip_bfloat16 h = __float2bfloat16(f);
  return *reinterpret_cast<unsigned short*>(&h);
}
__device__ __forceinline__ unsigned pk2(float lo, float hi) {
  return (unsigned)f2bf(lo) | ((unsigned)f2bf(hi) << 16);
}
__device__ __forceinline__ float bflo(unsigned u) { return __uint_as_float(u << 16); }
__device__ __forceinline__ float bfhi(unsigned u) { return __uint_as_float(u & 0xffff0000u); }

// ---------------- weight transpose+convert: WT[m][o][d] = bf16(W[m][d][o]) ----------------
__global__ __launch_bounds__(128) void convw_kernel(
    const float* __restrict__ W1, const float* __restrict__ Ws1,
    const float* __restrict__ W2, const float* __restrict__ Ws2,
    unsigned short* __restrict__ WT)
{
  const int m = blockIdx.y, o = blockIdx.x, d = threadIdx.x;
  const float* src;
  if (m < 8)       src = W1 + (size_t)m * DD * DD;
  else if (m == 8) src = Ws1;
  else if (m < 17) src = W2 + (size_t)(m - 9) * DD * DD;
  else             src = Ws2;
  WT[(size_t)m * DD * DD + o * DD + d] = f2bf(src[(size_t)d * DD + o]);
}

// ---------------- MFMA transform: one block = 64 rows, loops all 9 relations ----------------
// h read ONCE into registers; W[r] double-buffered in LDS (async reg-staged).
template<int AF32, int OUTF32>
__global__ __launch_bounds__(256) void transform_mfma(
    const void* __restrict__ hin, const int* __restrict__ ids,
    const unsigned short* __restrict__ WT,   // this layer's 9 mats, [m][o][d] bf16
    const float* __restrict__ bias,
    unsigned short* __restrict__ hr,
    void* __restrict__ outSelf)
{
  __shared__ __align__(16) char ldsW[2][DD * DD * 2];   // 2 x 32 KB, XOR-swizzled

  const int tid = threadIdx.x;
  const int rowBase = blockIdx.x * 64;
  const int lane = tid & 63;
  const int w = tid >> 6;
  const int c = lane & 15;          // n selector (B col) / o-local selector
  const int g = lane >> 4;          // k group
  const int n = rowBase + w * 16 + c;
  const int nld = (n < NN) ? n : (NN - 1);

  // ---- load h fragments once (registers, reused for all 9 relations) ----
  bf16x8 hfrag[4];
  if (AF32) {
    const int srcRow = ids[nld];
    const float* hrow = (const float*)hin + (size_t)srcRow * DD;
#pragma unroll
    for (int ks = 0; ks < 4; ++ks) {
      const float4 x = *reinterpret_cast<const float4*>(hrow + ks * 32 + g * 8);
      const float4 y = *reinterpret_cast<const float4*>(hrow + ks * 32 + g * 8 + 4);
      uint4 u;
      u.x = pk2(x.x, x.y); u.y = pk2(x.z, x.w);
      u.z = pk2(y.x, y.y); u.w = pk2(y.z, y.w);
      hfrag[ks] = *reinterpret_cast<bf16x8*>(&u);
    }
  } else {
    const unsigned short* hrow = (const unsigned short*)hin + (size_t)nld * DD;
#pragma unroll
    for (int ks = 0; ks < 4; ++ks) {
      uint4 u = *reinterpret_cast<const uint4*>(hrow + ks * 32 + g * 8);
      hfrag[ks] = *reinterpret_cast<bf16x8*>(&u);
    }
  }

  // ---- staging geometry: thread owns 8 x 16B chunks; dstB linear, src pre-inverse-swizzled ----
  // dstB = (tid + j*256)*16 ; srcB = dstB ^ (((dstB>>8)&7)<<4)  (involution)
  int srcOff[8];   // element offsets into a 128x128 bf16 matrix
#pragma unroll
  for (int j = 0; j < 8; ++j) {
    const int dstB = (tid + j * 256) * 16;
    const int srcB = dstB ^ (((dstB >> 8) & 7) << 4);
    srcOff[j] = srcB >> 1;
  }

  // prologue: load W[0] to regs, write buf0
  uint4 wreg[8];
#pragma unroll
  for (int j = 0; j < 8; ++j)
    wreg[j] = *reinterpret_cast<const uint4*>(WT + srcOff[j]);
#pragma unroll
  for (int j = 0; j < 8; ++j)
    *reinterpret_cast<uint4*>(ldsW[0] + (tid + j * 256) * 16) = wreg[j];

  for (int r = 0; r < NR + 1; ++r) {
    __syncthreads();                       // buf[r&1] ready; buf[r&1]^1 free
    const char* buf = ldsW[r & 1];

    // issue async loads for W[r+1] (land after MFMA+stores)
    if (r < NR) {
      const unsigned short* wnext = WT + (size_t)(r + 1) * DD * DD;
#pragma unroll
      for (int j = 0; j < 8; ++j)
        wreg[j] = *reinterpret_cast<const uint4*>(wnext + srcOff[j]);
    }

    // ---- MFMA ----
    f32x4 acc[8];
#pragma unroll
    for (int t = 0; t < 8; ++t) acc[t] = (f32x4){0.f, 0.f, 0.f, 0.f};
#pragma unroll
    for (int ks = 0; ks < 4; ++ks) {
#pragma unroll
      for (int t = 0; t < 8; ++t) {
        const int addr = (((t * 16 + c) << 8) + (ks << 6) + (g << 4)) ^ ((c & 7) << 4);
        bf16x8 a = *reinterpret_cast<const bf16x8*>(buf + addr);
        acc[t] = __builtin_amdgcn_mfma_f32_16x16x32_bf16(a, hfrag[ks], acc[t], 0, 0, 0);
      }
    }

    // ---- store output r ----
    if (n < NN) {
      if (r < NR) {
        unsigned short* dst = hr + ((size_t)r * NN + n) * DD;
#pragma unroll
        for (int t = 0; t < 8; ++t) {
          const int o0 = t * 16 + g * 4;
          uint2 u;
          u.x = pk2(acc[t][0], acc[t][1]);
          u.y = pk2(acc[t][2], acc[t][3]);
          *reinterpret_cast<uint2*>(dst + o0) = u;
        }
      } else if (OUTF32) {
        float* dst = (float*)outSelf + (size_t)n * DD;
#pragma unroll
        for (int t = 0; t < 8; ++t) {
          const int o0 = t * 16 + g * 4;
          const float4 bv = *reinterpret_cast<const float4*>(bias + o0);
          float4 o;
          o.x = acc[t][0] + bv.x; o.y = acc[t][1] + bv.y;
          o.z = acc[t][2] + bv.z; o.w = acc[t][3] + bv.w;
          *reinterpret_cast<float4*>(dst + o0) = o;
        }
      } else {
        unsigned short* dst = (unsigned short*)outSelf + (size_t)n * DD;
#pragma unroll
        for (int t = 0; t < 8; ++t) {
          const int o0 = t * 16 + g * 4;
          const float4 bv = *reinterpret_cast<const float4*>(bias + o0);
          uint2 u;
          u.x = pk2(acc[t][0] + bv.x, acc[t][1] + bv.y);
          u.y = pk2(acc[t][2] + bv.z, acc[t][3] + bv.w);
          *reinterpret_cast<uint2*>(dst + o0) = u;
        }
      }
    }

    // write next W into the other buffer (separated from its readers by next barrier)
    if (r < NR) {
      char* nbuf = ldsW[(r & 1) ^ 1];
#pragma unroll
      for (int j = 0; j < 8; ++j)
        *reinterpret_cast<uint4*>(nbuf + (tid + j * 256) * 16) = wreg[j];
    }
  }
}

// ---------------- CSR build (once per call) ----------------
__global__ __launch_bounds__(256) void hist_kernel(
    const int* __restrict__ dst, int* __restrict__ deg)
{
  const int e = blockIdx.x * 256 + threadIdx.x;
  if (e < NE) atomicAdd(&deg[dst[e]], 1);
}

__global__ __launch_bounds__(256) void bsum_kernel(
    const int* __restrict__ deg, int* __restrict__ bsum)
{
  __shared__ int tmp[256];
  const int t = threadIdx.x;
  const int i = blockIdx.x * 256 + t;
  tmp[t] = (i < NN) ? deg[i] : 0;
  __syncthreads();
#pragma unroll
  for (int off = 128; off > 0; off >>= 1) {
    if (t < off) tmp[t] += tmp[t + off];
    __syncthreads();
  }
  if (t == 0) bsum[blockIdx.x] = tmp[0];
}

__global__ __launch_bounds__(256) void bscan_kernel(
    const int* __restrict__ bsum, int* __restrict__ bbase)
{
  __shared__ int tmp[256];
  const int t = threadIdx.x;
  const int v = (t < NCHUNK) ? bsum[t] : 0;
  tmp[t] = v;
  __syncthreads();
#pragma unroll
  for (int off = 1; off < 256; off <<= 1) {
    const int x = (t >= off) ? tmp[t - off] : 0;
    __syncthreads();
    tmp[t] += x;
    __syncthreads();
  }
  if (t < NCHUNK) bbase[t] = tmp[t] - v;   // exclusive
}

__global__ __launch_bounds__(256) void expand_kernel(
    int* deg, const int* __restrict__ bbase, int* __restrict__ offsets)
{
  __shared__ int tmp[256];
  const int t = threadIdx.x;
  const int i = blockIdx.x * 256 + t;
  const int v = (i < NN) ? deg[i] : 0;
  tmp[t] = v;
  __syncthreads();
#pragma unroll
  for (int off = 1; off < 256; off <<= 1) {
    const int x = (t >= off) ? tmp[t - off] : 0;
    __syncthreads();
    tmp[t] += x;
    __syncthreads();
  }
  const int base = bbase[blockIdx.x];
  const int excl = base + tmp[t] - v;
  if (i < NN) {
    offsets[i] = excl;
    deg[i] = excl;                  // fill cursor
    if (i == NN - 1) offsets[NN] = base + tmp[t];
  }
}

__global__ __launch_bounds__(256) void fill_kernel(
    const int* __restrict__ src, const int* __restrict__ dst,
    const int* __restrict__ et, int* __restrict__ cursor,
    int* __restrict__ eidx)
{
  const int e = blockIdx.x * 256 + threadIdx.x;
  if (e < NE) {
    const int pos = atomicAdd(&cursor[dst[e]], 1);
    eidx[pos] = et[e] * NN + src[e];
  }
}

// ---------------- pull-mode aggregation ----------------
template<int BF16OUT>
__global__ __launch_bounds__(256) void aggregate_kernel(
    const unsigned short* __restrict__ hr,
    const int* __restrict__ offsets, const int* __restrict__ eidx,
    void* __restrict__ outv)
{
  const int node = blockIdx.x * 4 + (threadIdx.x >> 6);
  const int lane = threadIdx.x & 63;
  if (node >= NN) return;
  const int beg = offsets[node];
  const int end = offsets[node + 1];

  float a0 = 0.f, a1 = 0.f;
  int e = beg;
  for (; e + 3 < end; e += 4) {
    const int r0 = eidx[e], r1 = eidx[e + 1], r2 = eidx[e + 2], r3 = eidx[e + 3];
    const unsigned u0 = *reinterpret_cast<const unsigned*>(hr + (size_t)r0 * DD + lane * 2);
    const unsigned u1 = *reinterpret_cast<const unsigned*>(hr + (size_t)r1 * DD + lane * 2);
    const unsigned u2 = *reinterpret_cast<const unsigned*>(hr + (size_t)r2 * DD + lane * 2);
    const unsigned u3 = *reinterpret_cast<const unsigned*>(hr + (size_t)r3 * DD + lane * 2);
    a0 += (bflo(u0) + bflo(u1)) + (bflo(u2) + bflo(u3));
    a1 += (bfhi(u0) + bfhi(u1)) + (bfhi(u2) + bfhi(u3));
  }
  for (; e < end; ++e) {
    const unsigned u0 = *reinterpret_cast<const unsigned*>(hr + (size_t)eidx[e] * DD + lane * 2);
    a0 += bflo(u0);
    a1 += bfhi(u0);
  }

  if (BF16OUT) {
    unsigned* o = reinterpret_cast<unsigned*>((unsigned short*)outv + (size_t)node * DD + lane * 2);
    const unsigned u = *o;
    *o = pk2(bflo(u) + a0, bfhi(u) + a1);
  } else {
    float2* o = reinterpret_cast<float2*>((float*)outv + (size_t)node * DD + lane * 2);
    float2 v = *o;
    v.x += a0; v.y += a1;
    *o = v;
  }
}

extern "C" void kernel_launch(void* const* d_in, const int* in_sizes, int n_in,
                              void* d_out, int out_size, void* d_ws, size_t ws_size,
                              hipStream_t stream) {
  const int*   node_ids = (const int*)d_in[0];
  const int*   src   = (const int*)d_in[1];
  const int*   dst   = (const int*)d_in[2];
  const int*   etype = (const int*)d_in[3];
  const float* emb   = (const float*)d_in[4];
  const float* W1    = (const float*)d_in[5];
  const float* Ws1   = (const float*)d_in[6];
  const float* b1    = (const float*)d_in[7];
  const float* W2    = (const float*)d_in[8];
  const float* Ws2   = (const float*)d_in[9];
  const float* b2    = (const float*)d_in[10];

  // ws layout:
  //   hr     bf16 [R*NN*DD]       102.4 MB
  //   h1bf   bf16 [NN*DD]          12.8 MB
  //   WT     bf16 [18*DD*DD]        0.59 MB
  //   offsets i32 [NN+1], deg i32 [NN], eidx i32 [NE], bsum/bbase i32 [256] each
  char* p = (char*)d_ws;
  unsigned short* hr   = (unsigned short*)p;  p += (size_t)NR * NN * DD * 2;
  unsigned short* h1bf = (unsigned short*)p;  p += (size_t)NN * DD * 2;
  unsigned short* WT   = (unsigned short*)p;  p += (size_t)18 * DD * DD * 2;
  int* offsets         = (int*)p;             p += (size_t)(NN + 1) * 4;
  int* deg             = (int*)p;             p += (size_t)NN * 4;
  int* eidx            = (int*)p;             p += (size_t)NE * 4;
  int* bsum            = (int*)p;             p += 256 * 4;
  int* bbase           = (int*)p;

  const int eb = (NE + 255) / 256;
  const int tb = (NN + 63) / 64;   // 782
  const int ab = (NN + 3) / 4;

  // weight convert + CSR build
  convw_kernel<<<dim3(DD, 18), 128, 0, stream>>>(W1, Ws1, W2, Ws2, WT);
  hipMemsetAsync(deg, 0, (size_t)NN * 4, stream);
  hist_kernel<<<eb, 256, 0, stream>>>(dst, deg);
  bsum_kernel<<<NCHUNK, 256, 0, stream>>>(deg, bsum);
  bscan_kernel<<<1, 256, 0, stream>>>(bsum, bbase);
  expand_kernel<<<NCHUNK, 256, 0, stream>>>(deg, bbase, offsets);
  fill_kernel<<<eb, 256, 0, stream>>>(src, dst, etype, deg, eidx);

  // layer 1: A = emb[node_ids] (f32 gather), outputs bf16
  transform_mfma<1, 0><<<tb, 256, 0, stream>>>(emb, node_ids, WT, b1, hr, h1bf);
  aggregate_kernel<1><<<ab, 256, 0, stream>>>(hr, offsets, eidx, h1bf);
  // layer 2: A = h1 bf16, final output f32
  transform_mfma<0, 1><<<tb, 256, 0, stream>>>(h1bf, nullptr, WT + (size_t)9 * DD * DD, b2, hr, (float*)d_out);
  aggregate_kernel<0><<<ab, 256, 0, stream>>>(hr, offsets, eidx, (float*)d_out);
}

// Round 7
// 253.420 us; speedup vs baseline: 1.0734x; 1.0734x over previous
//
#include <hip/hip_runtime.h>
#include <hip/hip_bf16.h>

#define NN 50000
#define NE 600000
#define DD 128
#define NR 8
#define NCHUNK ((NN + 255) / 256)   // 196 scan blocks

typedef __attribute__((ext_vector_type(8))) short bf16x8;
typedef __attribute__((ext_vector_type(4))) float f32x4;

__device__ __forceinline__ unsigned short f2bf(float f) {
  __hip_bfloat16 h = __float2bfloat16(f);
  return *reinterpret_cast<unsigned short*>(&h);
}
__device__ __forceinline__ unsigned pk2(float lo, float hi) {
  return (unsigned)f2bf(lo) | ((unsigned)f2bf(hi) << 16);
}
__device__ __forceinline__ float bflo(unsigned u) { return __uint_as_float(u << 16); }
__device__ __forceinline__ float bfhi(unsigned u) { return __uint_as_float(u & 0xffff0000u); }

// ---------------- weight transpose+convert: WT[m][o][d] = bf16(W[m][d][o]) ----------------
__global__ __launch_bounds__(128) void convw_kernel(
    const float* __restrict__ W1, const float* __restrict__ Ws1,
    const float* __restrict__ W2, const float* __restrict__ Ws2,
    unsigned short* __restrict__ WT)
{
  const int m = blockIdx.y, o = blockIdx.x, d = threadIdx.x;
  const float* src;
  if (m < 8)       src = W1 + (size_t)m * DD * DD;
  else if (m == 8) src = Ws1;
  else if (m < 17) src = W2 + (size_t)(m - 9) * DD * DD;
  else             src = Ws2;
  WT[(size_t)m * DD * DD + o * DD + d] = f2bf(src[(size_t)d * DD + o]);
}

// ---------------- MFMA transform: one block = 128 rows, loops all 9 relations ----------------
// Each wave owns TWO 16-row n-tiles (one ds_read feeds 2 MFMAs).
// h read ONCE into registers; W[r] double-buffered in LDS (reg-staged prefetch).
template<int AF32, int OUTF32>
__global__ __launch_bounds__(256) void transform_mfma(
    const void* __restrict__ hin, const int* __restrict__ ids,
    const unsigned short* __restrict__ WT,   // this layer's 9 mats, [m][o][d] bf16
    const float* __restrict__ bias,
    unsigned short* __restrict__ hr,
    void* __restrict__ outSelf)
{
  __shared__ __align__(16) char ldsW[2][DD * DD * 2];   // 2 x 32 KB, XOR-swizzled

  const int tid = threadIdx.x;
  const int rowBase = blockIdx.x * 128;
  const int lane = tid & 63;
  const int w = tid >> 6;
  const int c = lane & 15;          // n selector (B col) / o-local selector
  const int g = lane >> 4;          // k group
  int nn[2], nld[2];
#pragma unroll
  for (int u = 0; u < 2; ++u) {
    nn[u] = rowBase + w * 32 + u * 16 + c;
    nld[u] = (nn[u] < NN) ? nn[u] : (NN - 1);
  }

  // ---- load h fragments once (registers, reused for all 9 relations) ----
  bf16x8 hfrag[2][4];
#pragma unroll
  for (int u = 0; u < 2; ++u) {
    if (AF32) {
      const int srcRow = ids[nld[u]];
      const float* hrow = (const float*)hin + (size_t)srcRow * DD;
#pragma unroll
      for (int ks = 0; ks < 4; ++ks) {
        const float4 x = *reinterpret_cast<const float4*>(hrow + ks * 32 + g * 8);
        const float4 y = *reinterpret_cast<const float4*>(hrow + ks * 32 + g * 8 + 4);
        uint4 q;
        q.x = pk2(x.x, x.y); q.y = pk2(x.z, x.w);
        q.z = pk2(y.x, y.y); q.w = pk2(y.z, y.w);
        hfrag[u][ks] = *reinterpret_cast<bf16x8*>(&q);
      }
    } else {
      const unsigned short* hrow = (const unsigned short*)hin + (size_t)nld[u] * DD;
#pragma unroll
      for (int ks = 0; ks < 4; ++ks) {
        uint4 q = *reinterpret_cast<const uint4*>(hrow + ks * 32 + g * 8);
        hfrag[u][ks] = *reinterpret_cast<bf16x8*>(&q);
      }
    }
  }

  // ---- staging geometry: thread owns 8 x 16B chunks; dstB linear, src pre-inverse-swizzled ----
  int srcOff[8];
#pragma unroll
  for (int j = 0; j < 8; ++j) {
    const int dstB = (tid + j * 256) * 16;
    const int srcB = dstB ^ (((dstB >> 8) & 7) << 4);
    srcOff[j] = srcB >> 1;
  }

  // prologue: load W[0] to regs, write buf0
  uint4 wreg[8];
#pragma unroll
  for (int j = 0; j < 8; ++j)
    wreg[j] = *reinterpret_cast<const uint4*>(WT + srcOff[j]);
#pragma unroll
  for (int j = 0; j < 8; ++j)
    *reinterpret_cast<uint4*>(ldsW[0] + (tid + j * 256) * 16) = wreg[j];

  for (int r = 0; r < NR + 1; ++r) {
    __syncthreads();                       // buf[r&1] ready; other buf free
    const char* buf = ldsW[r & 1];

    // issue loads for W[r+1] (land during MFMA+stores)
    if (r < NR) {
      const unsigned short* wnext = WT + (size_t)(r + 1) * DD * DD;
#pragma unroll
      for (int j = 0; j < 8; ++j)
        wreg[j] = *reinterpret_cast<const uint4*>(wnext + srcOff[j]);
    }

    // ---- MFMA: one ds_read feeds both n-tiles ----
    f32x4 acc[2][8];
#pragma unroll
    for (int u = 0; u < 2; ++u)
#pragma unroll
      for (int t = 0; t < 8; ++t) acc[u][t] = (f32x4){0.f, 0.f, 0.f, 0.f};
#pragma unroll
    for (int ks = 0; ks < 4; ++ks) {
#pragma unroll
      for (int t = 0; t < 8; ++t) {
        const int addr = (((t * 16 + c) << 8) + (ks << 6) + (g << 4)) ^ ((c & 7) << 4);
        bf16x8 a = *reinterpret_cast<const bf16x8*>(buf + addr);
        acc[0][t] = __builtin_amdgcn_mfma_f32_16x16x32_bf16(a, hfrag[0][ks], acc[0][t], 0, 0, 0);
        acc[1][t] = __builtin_amdgcn_mfma_f32_16x16x32_bf16(a, hfrag[1][ks], acc[1][t], 0, 0, 0);
      }
    }

    // ---- store outputs for both tiles ----
#pragma unroll
    for (int u = 0; u < 2; ++u) {
      const int n = nn[u];
      if (n >= NN) continue;
      if (r < NR) {
        unsigned short* dst = hr + ((size_t)r * NN + n) * DD;
#pragma unroll
        for (int t = 0; t < 8; ++t) {
          const int o0 = t * 16 + g * 4;
          uint2 q;
          q.x = pk2(acc[u][t][0], acc[u][t][1]);
          q.y = pk2(acc[u][t][2], acc[u][t][3]);
          *reinterpret_cast<uint2*>(dst + o0) = q;
        }
      } else if (OUTF32) {
        float* dst = (float*)outSelf + (size_t)n * DD;
#pragma unroll
        for (int t = 0; t < 8; ++t) {
          const int o0 = t * 16 + g * 4;
          const float4 bv = *reinterpret_cast<const float4*>(bias + o0);
          float4 o;
          o.x = acc[u][t][0] + bv.x; o.y = acc[u][t][1] + bv.y;
          o.z = acc[u][t][2] + bv.z; o.w = acc[u][t][3] + bv.w;
          *reinterpret_cast<float4*>(dst + o0) = o;
        }
      } else {
        unsigned short* dst = (unsigned short*)outSelf + (size_t)n * DD;
#pragma unroll
        for (int t = 0; t < 8; ++t) {
          const int o0 = t * 16 + g * 4;
          const float4 bv = *reinterpret_cast<const float4*>(bias + o0);
          uint2 q;
          q.x = pk2(acc[u][t][0] + bv.x, acc[u][t][1] + bv.y);
          q.y = pk2(acc[u][t][2] + bv.z, acc[u][t][3] + bv.w);
          *reinterpret_cast<uint2*>(dst + o0) = q;
        }
      }
    }

    // write next W into the other buffer (readers separated by next barrier)
    if (r < NR) {
      char* nbuf = ldsW[(r & 1) ^ 1];
#pragma unroll
      for (int j = 0; j < 8; ++j)
        *reinterpret_cast<uint4*>(nbuf + (tid + j * 256) * 16) = wreg[j];
    }
  }
}

// ---------------- CSR build (once per call) ----------------
__global__ __launch_bounds__(256) void hist_kernel(
    const int* __restrict__ dst, int* __restrict__ deg)
{
  const int e = blockIdx.x * 256 + threadIdx.x;
  if (e < NE) atomicAdd(&deg[dst[e]], 1);
}

__global__ __launch_bounds__(256) void bsum_kernel(
    const int* __restrict__ deg, int* __restrict__ bsum)
{
  __shared__ int tmp[256];
  const int t = threadIdx.x;
  const int i = blockIdx.x * 256 + t;
  tmp[t] = (i < NN) ? deg[i] : 0;
  __syncthreads();
#pragma unroll
  for (int off = 128; off > 0; off >>= 1) {
    if (t < off) tmp[t] += tmp[t + off];
    __syncthreads();
  }
  if (t == 0) bsum[blockIdx.x] = tmp[0];
}

__global__ __launch_bounds__(256) void bscan_kernel(
    const int* __restrict__ bsum, int* __restrict__ bbase)
{
  __shared__ int tmp[256];
  const int t = threadIdx.x;
  const int v = (t < NCHUNK) ? bsum[t] : 0;
  tmp[t] = v;
  __syncthreads();
#pragma unroll
  for (int off = 1; off < 256; off <<= 1) {
    const int x = (t >= off) ? tmp[t - off] : 0;
    __syncthreads();
    tmp[t] += x;
    __syncthreads();
  }
  if (t < NCHUNK) bbase[t] = tmp[t] - v;   // exclusive
}

__global__ __launch_bounds__(256) void expand_kernel(
    int* deg, const int* __restrict__ bbase, int* __restrict__ offsets)
{
  __shared__ int tmp[256];
  const int t = threadIdx.x;
  const int i = blockIdx.x * 256 + t;
  const int v = (i < NN) ? deg[i] : 0;
  tmp[t] = v;
  __syncthreads();
#pragma unroll
  for (int off = 1; off < 256; off <<= 1) {
    const int x = (t >= off) ? tmp[t - off] : 0;
    __syncthreads();
    tmp[t] += x;
    __syncthreads();
  }
  const int base = bbase[blockIdx.x];
  const int excl = base + tmp[t] - v;
  if (i < NN) {
    offsets[i] = excl;
    deg[i] = excl;                  // fill cursor
    if (i == NN - 1) offsets[NN] = base + tmp[t];
  }
}

__global__ __launch_bounds__(256) void fill_kernel(
    const int* __restrict__ src, const int* __restrict__ dst,
    const int* __restrict__ et, int* __restrict__ cursor,
    int* __restrict__ eidx)
{
  const int e = blockIdx.x * 256 + threadIdx.x;
  if (e < NE) {
    const int pos = atomicAdd(&cursor[dst[e]], 1);
    eidx[pos] = et[e] * NN + src[e];
  }
}

// ---------------- pull-mode aggregation ----------------
template<int BF16OUT>
__global__ __launch_bounds__(256) void aggregate_kernel(
    const unsigned short* __restrict__ hr,
    const int* __restrict__ offsets, const int* __restrict__ eidx,
    void* __restrict__ outv)
{
  const int node = blockIdx.x * 4 + (threadIdx.x >> 6);
  const int lane = threadIdx.x & 63;
  if (node >= NN) return;
  const int beg = offsets[node];
  const int end = offsets[node + 1];

  float a0 = 0.f, a1 = 0.f;
  int e = beg;
  for (; e + 3 < end; e += 4) {
    const int r0 = eidx[e], r1 = eidx[e + 1], r2 = eidx[e + 2], r3 = eidx[e + 3];
    const unsigned u0 = *reinterpret_cast<const unsigned*>(hr + (size_t)r0 * DD + lane * 2);
    const unsigned u1 = *reinterpret_cast<const unsigned*>(hr + (size_t)r1 * DD + lane * 2);
    const unsigned u2 = *reinterpret_cast<const unsigned*>(hr + (size_t)r2 * DD + lane * 2);
    const unsigned u3 = *reinterpret_cast<const unsigned*>(hr + (size_t)r3 * DD + lane * 2);
    a0 += (bflo(u0) + bflo(u1)) + (bflo(u2) + bflo(u3));
    a1 += (bfhi(u0) + bfhi(u1)) + (bfhi(u2) + bfhi(u3));
  }
  for (; e < end; ++e) {
    const unsigned u0 = *reinterpret_cast<const unsigned*>(hr + (size_t)eidx[e] * DD + lane * 2);
    a0 += bflo(u0);
    a1 += bfhi(u0);
  }

  if (BF16OUT) {
    unsigned* o = reinterpret_cast<unsigned*>((unsigned short*)outv + (size_t)node * DD + lane * 2);
    const unsigned u = *o;
    *o = pk2(bflo(u) + a0, bfhi(u) + a1);
  } else {
    float2* o = reinterpret_cast<float2*>((float*)outv + (size_t)node * DD + lane * 2);
    float2 v = *o;
    v.x += a0; v.y += a1;
    *o = v;
  }
}

extern "C" void kernel_launch(void* const* d_in, const int* in_sizes, int n_in,
                              void* d_out, int out_size, void* d_ws, size_t ws_size,
                              hipStream_t stream) {
  const int*   node_ids = (const int*)d_in[0];
  const int*   src   = (const int*)d_in[1];
  const int*   dst   = (const int*)d_in[2];
  const int*   etype = (const int*)d_in[3];
  const float* emb   = (const float*)d_in[4];
  const float* W1    = (const float*)d_in[5];
  const float* Ws1   = (const float*)d_in[6];
  const float* b1    = (const float*)d_in[7];
  const float* W2    = (const float*)d_in[8];
  const float* Ws2   = (const float*)d_in[9];
  const float* b2    = (const float*)d_in[10];

  // ws layout:
  //   hr     bf16 [R*NN*DD]       102.4 MB
  //   h1bf   bf16 [NN*DD]          12.8 MB
  //   WT     bf16 [18*DD*DD]        0.59 MB
  //   offsets i32 [NN+1], deg i32 [NN], eidx i32 [NE], bsum/bbase i32 [256] each
  char* p = (char*)d_ws;
  unsigned short* hr   = (unsigned short*)p;  p += (size_t)NR * NN * DD * 2;
  unsigned short* h1bf = (unsigned short*)p;  p += (size_t)NN * DD * 2;
  unsigned short* WT   = (unsigned short*)p;  p += (size_t)18 * DD * DD * 2;
  int* offsets         = (int*)p;             p += (size_t)(NN + 1) * 4;
  int* deg             = (int*)p;             p += (size_t)NN * 4;
  int* eidx            = (int*)p;             p += (size_t)NE * 4;
  int* bsum            = (int*)p;             p += 256 * 4;
  int* bbase           = (int*)p;

  const int eb = (NE + 255) / 256;
  const int tb = (NN + 127) / 128;   // 391
  const int ab = (NN + 3) / 4;

  // weight convert + CSR build
  convw_kernel<<<dim3(DD, 18), 128, 0, stream>>>(W1, Ws1, W2, Ws2, WT);
  hipMemsetAsync(deg, 0, (size_t)NN * 4, stream);
  hist_kernel<<<eb, 256, 0, stream>>>(dst, deg);
  bsum_kernel<<<NCHUNK, 256, 0, stream>>>(deg, bsum);
  bscan_kernel<<<1, 256, 0, stream>>>(bsum, bbase);
  expand_kernel<<<NCHUNK, 256, 0, stream>>>(deg, bbase, offsets);
  fill_kernel<<<eb, 256, 0, stream>>>(src, dst, etype, deg, eidx);

  // layer 1: A = emb[node_ids] (f32 gather), outputs bf16
  transform_mfma<1, 0><<<tb, 256, 0, stream>>>(emb, node_ids, WT, b1, hr, h1bf);
  aggregate_kernel<1><<<ab, 256, 0, stream>>>(hr, offsets, eidx, h1bf);
  // layer 2: A = h1 bf16, final output f32
  transform_mfma<0, 1><<<tb, 256, 0, stream>>>(h1bf, nullptr, WT + (size_t)9 * DD * DD, b2, hr, (float*)d_out);
  aggregate_kernel<0><<<ab, 256, 0, stream>>>(hr, offsets, eidx, (float*)d_out);
}